// Round 15
// baseline (912.757 us; speedup 1.0000x reference)
//
#include <hip/hip_runtime.h>
#include <math.h>

#define HIDDEN 512
#define WINDOW 24
#define KSZ 3
#define BATCH 2048
#define L_IN 514
#define H4 2048
#define LDT 40                    // padded LDS row stride (shorts) for 32-k tiles
#define BH (BATCH * HIDDEN)

typedef short short8 __attribute__((ext_vector_type(8)));
typedef float floatx4 __attribute__((ext_vector_type(4)));

__device__ __forceinline__ floatx4 mfma16(short8 a, short8 b, floatx4 c) {
    return __builtin_amdgcn_mfma_f32_16x16x32_bf16(a, b, c, 0, 0, 0);
}
__device__ __forceinline__ unsigned short f2bf(float x) {
    union { float f; unsigned u; } v; v.f = x;
    unsigned r = v.u + 0x7fff + ((v.u >> 16) & 1);   // RTNE
    return (unsigned short)(r >> 16);
}
__device__ __forceinline__ float bf2f(unsigned short u) {
    union { unsigned u; float f; } v; v.u = ((unsigned)u) << 16;
    return v.f;
}
__device__ __forceinline__ float sigmoidf(float x) { return 1.f / (1.f + expf(-x)); }

// Direct global->LDS DMA, 16 B per lane (dest = wave-uniform base + lane*16).
__device__ __forceinline__ void gload_lds16(const void* g, void* l) {
    __builtin_amdgcn_global_load_lds(
        (const __attribute__((address_space(1))) void*)g,
        (__attribute__((address_space(3))) void*)l, 16, 0, 0);
}

// ---------------------------------------------------------------------------
// cvt5 + init (verbatim R14): fp32 -> bf16 for Wd, Ud, Whh, d_init, s_init;
// tail blocks do init work. Whh gate-interleaved repack [validated R6].
// ---------------------------------------------------------------------------
__global__ void cvt5_kernel(const float* __restrict__ s0, unsigned short* __restrict__ d0,
                            const float* __restrict__ s1, unsigned short* __restrict__ d1,
                            const float* __restrict__ s2, unsigned short* __restrict__ d2,
                            const float* __restrict__ s3, unsigned short* __restrict__ d3,
                            const float* __restrict__ s4, unsigned short* __restrict__ d4,
                            const float* __restrict__ y_real, const float* __restrict__ w,
                            float* __restrict__ yr_dot, float* __restrict__ Sacc,
                            int* __restrict__ flags, float* __restrict__ ctwA) {
    const int g = blockIdx.x * blockDim.x + threadIdx.x;   // one float4 per thread
    if (g >= 983040) {                                     // init tail: 2048 threads
        const int tid = g - 983040;
        if (tid < BATCH) {
            float s = 0.f;
#pragma unroll
            for (int j = 0; j < WINDOW; ++j) s += y_real[tid * WINDOW + j] * w[j];
            yr_dot[tid] = s;
        }
        if (tid < 2 * WINDOW) Sacc[tid] = 0.f;
        if (tid < WINDOW) flags[tid] = 0;
        if (tid == 0) ctwA[0] = 0.f;
        return;
    }
    const float* src; unsigned short* dst; int off, offd;
    if      (g < 131072) { src = s0; dst = d0; off = g; offd = off; }
    else if (g < 196608) { src = s1; dst = d1; off = g - 131072; offd = off; }
    else if (g < 458752) {
        src = s2; dst = d2; off = g - 196608;
        const int row = off >> 7, seg = off & 127;       // 128 float4 per 512-col row
        const int gg = row >> 9, ii = row & 511;
        const int drow = ((ii >> 4) << 6) + (gg << 4) + (ii & 15);
        offd = drow * 128 + seg;
    }
    else if (g < 720896) { src = s3; dst = d3; off = g - 458752; offd = off; }
    else                 { src = s4; dst = d4; off = g - 720896; offd = off; }
    float4 v = ((const float4*)src)[off];
    uint2 u;
    u.x = (unsigned)f2bf(v.x) | ((unsigned)f2bf(v.y) << 16);
    u.y = (unsigned)f2bf(v.z) | ((unsigned)f2bf(v.w) << 16);
    ((uint2*)dst)[offd] = u;
}

// ---------------------------------------------------------------------------
// conv1d + bias + relu -> Htb bf16 [t][b][i]; FUSED hw (verbatim R14).
// ---------------------------------------------------------------------------
__global__ void conv_kernel(const float* __restrict__ Z, const float* __restrict__ conv_w,
                            const float* __restrict__ conv_b,
                            unsigned int* __restrict__ Htu,
                            const float* __restrict__ w, float* __restrict__ hw) {
    __shared__ float cw[WINDOW * 6];
    __shared__ float cb[WINDOW];
    __shared__ float sm[WINDOW][4];
    const int b = blockIdx.x;
    if (threadIdx.x < WINDOW * 6) cw[threadIdx.x] = conv_w[threadIdx.x];
    if (threadIdx.x < WINDOW) cb[threadIdx.x] = conv_b[threadIdx.x];
    __syncthreads();
    const float* z0 = Z + (size_t)b * L_IN;
    const float* z1 = z0 + (size_t)BATCH * L_IN;
    const int i0 = threadIdx.x * 2;
    const int wave = threadIdx.x >> 6;
    const float a0 = z0[i0], a1 = z0[i0 + 1], a2 = z0[i0 + 2], a3 = z0[i0 + 3];
    const float c0 = z1[i0], c1 = z1[i0 + 1], c2 = z1[i0 + 2], c3 = z1[i0 + 3];
    const float wv0 = w[WINDOW + i0], wv1 = w[WINDOW + i0 + 1];
#pragma unroll
    for (int o = 0; o < WINDOW; ++o) {
        const float* wc = cw + o * 6;
        float v0 = fmaxf(cb[o] + a0 * wc[0] + a1 * wc[1] + a2 * wc[2]
                               + c0 * wc[3] + c1 * wc[4] + c2 * wc[5], 0.f);
        float v1 = fmaxf(cb[o] + a1 * wc[0] + a2 * wc[1] + a3 * wc[2]
                               + c1 * wc[3] + c2 * wc[4] + c3 * wc[5], 0.f);
        const unsigned short h0 = f2bf(v0), h1 = f2bf(v1);
        Htu[((size_t)o * BATCH + b) * 256 + threadIdx.x] =
            (unsigned)h0 | ((unsigned)h1 << 16);
        float c = bf2f(h0) * wv0 + bf2f(h1) * wv1;
#pragma unroll
        for (int m = 1; m < 64; m <<= 1) c += __shfl_xor(c, m, 64);
        if ((threadIdx.x & 63) == 0) sm[o][wave] = c;
    }
    __syncthreads();
    if (threadIdx.x < WINDOW)
        hw[(size_t)threadIdx.x * BATCH + b] =
            sm[threadIdx.x][0] + sm[threadIdx.x][1] + sm[threadIdx.x][2] + sm[threadIdx.x][3];
}

// ---------------------------------------------------------------------------
// Gb = Htb @ Udb^T (verbatim R14 — measured good): 128x128, BK=64, gload_lds
// with both-sides permutation, XCD-clustered swizzle.
// ---------------------------------------------------------------------------
__global__ __launch_bounds__(256) void g_gemm_mfma(const unsigned short* __restrict__ Htb,
                                                   const unsigned short* __restrict__ Udb,
                                                   unsigned short* __restrict__ Gb) {
    __shared__ __align__(16) short As[2 * 8 * 512];   // 2 panels x 8 chunks x 1 KB
    __shared__ __align__(16) short Bs[2 * 8 * 512];
    const int blk = blockIdx.x;                 // 0..1535
    const int xcd = blk & 7;
    const int grp = blk >> 3;                   // 0..191
    const int nt  = grp & 3;                    // n-tile 0..3 (inner on one XCD)
    const int mt  = (grp >> 2) * 8 + xcd;       // m-tile 0..383
    const int tid = threadIdx.x;
    const int wave = tid >> 6, lane = tid & 63;
    const int wm = wave >> 1, wn = wave & 1;
    const int quad = lane >> 4, lr = lane & 15;
    const int m0 = mt * 128, n0 = nt * 128;
    const int wr = lane >> 2;                 // row within 16-row chunk
    const int ws = (lane & 3) ^ (lane >> 4);  // permuted k-seg
    const int rsw = (lr * 4 + (quad ^ (lr >> 2))) * 8;
    floatx4 acc[4][4] = {};
    for (int k0 = 0; k0 < HIDDEN; k0 += 64) {
#pragma unroll
        for (int c8 = 0; c8 < 8; ++c8) {
            const int cc = wave * 8 + c8;          // 0..31
            const int cc2 = cc & 15;
            const int h = cc2 >> 3, ch = cc2 & 7;
            if (cc < 16)
                gload_lds16(Htb + (size_t)(m0 + ch * 16 + wr) * HIDDEN + k0 + 32 * h + ws * 8,
                            As + (h * 8 + ch) * 512);
            else
                gload_lds16(Udb + (size_t)(n0 + ch * 16 + wr) * HIDDEN + k0 + 32 * h + ws * 8,
                            Bs + (h * 8 + ch) * 512);
        }
        __syncthreads();
#pragma unroll
        for (int h = 0; h < 2; ++h) {
            short8 a[4], bv[4];
#pragma unroll
            for (int f = 0; f < 4; ++f) {
                a[f]  = *(const short8*)(As + (h * 8 + wm * 4 + f) * 512 + rsw);
                bv[f] = *(const short8*)(Bs + (h * 8 + wn * 4 + f) * 512 + rsw);
            }
#pragma unroll
            for (int mf = 0; mf < 4; ++mf)
#pragma unroll
                for (int nf = 0; nf < 4; ++nf)
                    acc[mf][nf] = mfma16(a[mf], bv[nf], acc[mf][nf]);
        }
        __syncthreads();
    }
#pragma unroll
    for (int mf = 0; mf < 4; ++mf)
#pragma unroll
        for (int nf = 0; nf < 4; ++nf)
#pragma unroll
            for (int r = 0; r < 4; ++r) {
                const int m = m0 + wm * 64 + mf * 16 + quad * 4 + r;
                const int n = n0 + wn * 64 + nf * 16 + lr;
                Gb[(size_t)m * HIDDEN + n] = f2bf(acc[mf][nf][r]);
            }
}

// ---------------------------------------------------------------------------
// S1, merged passes, BK=64, split accumulators (verbatim R13/R14 — passed).
// ---------------------------------------------------------------------------
__global__ __launch_bounds__(256) void s1_mfma(const unsigned short* __restrict__ db,
                                               const unsigned short* __restrict__ sb,
                                               const unsigned short* __restrict__ Wdb,
                                               const unsigned short* __restrict__ Gtb,
                                               const float* __restrict__ vd,
                                               float* __restrict__ lpart) {
    __shared__ __align__(16) short Asd[2][64 * LDT];
    __shared__ __align__(16) short Ass[2][64 * LDT];
    __shared__ __align__(16) short Bsd[2][32 * LDT];
    __shared__ __align__(16) short Bss[2][32 * LDT];
    __shared__ float red[2][64];
    const int tid = threadIdx.x;
    const int wave = tid >> 6, lane = tid & 63;
    const int wm = wave >> 1, wn = wave & 1;
    const int quad = lane >> 4, lr = lane & 15, qk = quad * 8;
    const int m0 = (blockIdx.x & 31) * 64;
    const int nb = blockIdx.x >> 5;          // 0..15
    const int n0 = nb * 32;
    const int arow = tid >> 2, aseg = tid & 3;
    floatx4 accd[2] = {}, accs[2] = {};
    for (int k0 = 0; k0 < HIDDEN; k0 += 64) {
#pragma unroll
        for (int h = 0; h < 2; ++h) {
            const int kk = k0 + 32 * h;
            *(float4*)(Asd[h] + arow * LDT + aseg * 8) =
                *(const float4*)(db + (size_t)(m0 + arow) * HIDDEN + kk + aseg * 8);
            *(float4*)(Ass[h] + arow * LDT + aseg * 8) =
                *(const float4*)(sb + (size_t)(m0 + arow) * HIDDEN + kk + aseg * 8);
            const int r2 = tid & 127, brow = r2 >> 2, bseg = r2 & 3;
            short* dst = (tid < 128) ? Bsd[h] : Bss[h];
            const int coff = (tid < 128) ? 0 : HIDDEN;
            *(float4*)(dst + brow * LDT + bseg * 8) =
                *(const float4*)(Wdb + (size_t)(n0 + brow) * (2 * HIDDEN) + coff + kk + bseg * 8);
        }
        __syncthreads();
#pragma unroll
        for (int h = 0; h < 2; ++h) {
            short8 ad0 = *(const short8*)(Asd[h] + (wm * 32 + lr) * LDT + qk);
            short8 ad1 = *(const short8*)(Asd[h] + (wm * 32 + 16 + lr) * LDT + qk);
            short8 as0 = *(const short8*)(Ass[h] + (wm * 32 + lr) * LDT + qk);
            short8 as1 = *(const short8*)(Ass[h] + (wm * 32 + 16 + lr) * LDT + qk);
            short8 bd  = *(const short8*)(Bsd[h] + (wn * 16 + lr) * LDT + qk);
            short8 bs  = *(const short8*)(Bss[h] + (wn * 16 + lr) * LDT + qk);
            accd[0] = mfma16(ad0, bd, accd[0]);
            accd[1] = mfma16(ad1, bd, accd[1]);
            accs[0] = mfma16(as0, bs, accs[0]);
            accs[1] = mfma16(as1, bs, accs[1]);
        }
        __syncthreads();
    }
#pragma unroll
    for (int mf = 0; mf < 2; ++mf) {
        float rs[4];
#pragma unroll
        for (int r = 0; r < 4; ++r) {
            const int b = m0 + wm * 32 + mf * 16 + quad * 4 + r;
            const int i = n0 + wn * 16 + lr;
            float v = tanhf(accd[mf][r] + accs[mf][r] + bf2f(Gtb[(size_t)b * HIDDEN + i])) * vd[i];
            for (int msk = 1; msk < 16; msk <<= 1) v += __shfl_xor(v, msk, 16);
            rs[r] = v;
        }
        if (lr == 0)
#pragma unroll
            for (int r = 0; r < 4; ++r)
                red[wn][wm * 32 + mf * 16 + quad * 4 + r] = rs[r];
    }
    __syncthreads();
    if (tid < 64)
        lpart[(size_t)nb * BATCH + m0 + tid] = red[0][tid] + red[1][tid];
}

// ---------------------------------------------------------------------------
// gates+mid+LSTM: NEW 64x64 tile, 1024 blocks (4 blocks/CU — extends the
// proven R9->R10 occupancy lever). Each wave owns 16 b-rows x all 64
// gate-interleaved cols (1 A-frag x 4 B-frags, acc[4] = one per gate), so
// the all-4-gates-per-thread epilogue survives. Fold/flag protocol verbatim
// (32 nt==0 blocks, target 32). gload_lds + both-sides permutation (R12).
// ---------------------------------------------------------------------------
__global__ __launch_bounds__(256) void gates_lstm_mfma(
        const unsigned short* __restrict__ db, const unsigned short* __restrict__ Whhb,
        const float* __restrict__ Wih, const float* __restrict__ bih,
        const float* __restrict__ bhh, const float* __restrict__ yr_dot,
        const float* __restrict__ lpart, const float* __restrict__ hw_t,
        float* __restrict__ Sacc, int* __restrict__ flags,
        float* __restrict__ ctwA, const float* __restrict__ b00,
        const float* __restrict__ s_old, float* __restrict__ s_new,
        float* __restrict__ d_new,
        unsigned short* __restrict__ sb_new, unsigned short* __restrict__ db_new,
        float* __restrict__ y_out, int t) {
    __shared__ __align__(16) short As[2 * 4 * 512];     // 2 panels x 4 chunks x 1 KB
    __shared__ __align__(16) short Bs[2 * 4 * 512];
    __shared__ float sSe[2];
    const int tid = threadIdx.x;
    const int wave = tid >> 6, lane = tid & 63;
    const int quad = lane >> 4, lr = lane & 15;
    const int mt = blockIdx.x & 31, nt = blockIdx.x >> 5;   // 32 x 32
    const int m0 = mt * 64, n0 = nt * 64;

    // --- mid fold: nt==0 blocks (32) reduce their 64 b-rows of lpart ---
    if (nt == 0 && tid < 64) {
        const int b = m0 + tid;
        float l = 0.f;
#pragma unroll
        for (int p = 0; p < 16; ++p) l += lpart[(size_t)p * BATCH + b];
        float e = expf(l);
        float eh = e * hw_t[b];
#pragma unroll
        for (int m = 1; m < 64; m <<= 1) {
            e  += __shfl_xor(e, m, 64);
            eh += __shfl_xor(eh, m, 64);
        }
        if (tid == 0) {
            __hip_atomic_fetch_add(&Sacc[2 * t], e, __ATOMIC_RELAXED, __HIP_MEMORY_SCOPE_AGENT);
            __hip_atomic_fetch_add(&Sacc[2 * t + 1], eh, __ATOMIC_RELAXED, __HIP_MEMORY_SCOPE_AGENT);
        }
    }
    __syncthreads();   // drains wave0's atomic adds
    if (nt == 0 && tid == 0)
        __hip_atomic_fetch_add(&flags[t], 1, __ATOMIC_RELEASE, __HIP_MEMORY_SCOPE_AGENT);

    // writer-side permutation (per-lane global source for linear LDS dest)
    const int wr = lane >> 2;                 // row within 16-row chunk
    const int ws = (lane & 3) ^ (lane >> 4);  // permuted k-seg
    // reader-side: swizzled short-offset within a chunk
    const int rsw = (lr * 4 + (quad ^ (lr >> 2))) * 8;

    // --- gates GEMM: C[64 b][64 n], n = gate-interleaved (one 16-i group) ---
    floatx4 acc[4] = {};   // [gate]
    for (int k0 = 0; k0 < HIDDEN; k0 += 64) {
        // 16 chunk-DMAs per iteration, 4 per wave (waves 0,1: A; 2,3: B)
#pragma unroll
        for (int c4 = 0; c4 < 4; ++c4) {
            const int cc = wave * 4 + c4;          // 0..15
            const int h = (cc >> 2) & 1, ch = cc & 3;
            if (cc < 8)
                gload_lds16(db + (size_t)(m0 + ch * 16 + wr) * HIDDEN + k0 + 32 * h + ws * 8,
                            As + (h * 4 + ch) * 512);
            else
                gload_lds16(Whhb + (size_t)(n0 + ch * 16 + wr) * HIDDEN + k0 + 32 * h + ws * 8,
                            Bs + (h * 4 + ch) * 512);
        }
        __syncthreads();
#pragma unroll
        for (int h = 0; h < 2; ++h) {
            short8 a0 = *(const short8*)(As + (h * 4 + wave) * 512 + rsw);
#pragma unroll
            for (int f = 0; f < 4; ++f) {
                short8 bv = *(const short8*)(Bs + (h * 4 + f) * 512 + rsw);
                acc[f] = mfma16(a0, bv, acc[f]);
            }
        }
        __syncthreads();
    }

    // --- acquire softmax totals (GEMM hid the wait) ---
    if (tid == 0) {
        while (__hip_atomic_load(&flags[t], __ATOMIC_ACQUIRE, __HIP_MEMORY_SCOPE_AGENT) < 32)
            __builtin_amdgcn_s_sleep(2);
        sSe[0] = __hip_atomic_load(&Sacc[2 * t], __ATOMIC_RELAXED, __HIP_MEMORY_SCOPE_AGENT);
        sSe[1] = __hip_atomic_load(&Sacc[2 * t + 1], __ATOMIC_RELAXED, __HIP_MEMORY_SCOPE_AGENT);
    }
    __syncthreads();
    const float ctw = ctwA[t] + sSe[1] / sSe[0];
    const float ys = ctw + b00[0];
    if (blockIdx.x == 0 && tid == 0) ctwA[t + 1] = ctw;   // next launch reads (plain)
    if (y_out != nullptr && nt == 0 && tid < 64)
        y_out[m0 + tid] = yr_dot[m0 + tid] + ys;

    // --- fused LSTM epilogue: thread owns one i (= nt*16 + lr), all 4 gates ---
    const int i = nt * 16 + lr;
    float wi4[4], cbv[4];
#pragma unroll
    for (int g = 0; g < 4; ++g) {
        wi4[g] = Wih[g * HIDDEN + i];
        cbv[g] = bih[g * HIDDEN + i] + bhh[g * HIDDEN + i];
    }
#pragma unroll
    for (int r = 0; r < 4; ++r) {
        const int b = m0 + wave * 16 + quad * 4 + r;
        const float yf = yr_dot[b] + ys;
        const size_t idx = (size_t)b * HIDDEN + i;
        const float ig = acc[0][r] + yf * wi4[0] + cbv[0];
        const float fg = acc[1][r] + yf * wi4[1] + cbv[1];
        const float gg = acc[2][r] + yf * wi4[2] + cbv[2];
        const float og = acc[3][r] + yf * wi4[3] + cbv[3];
        const float sn = sigmoidf(fg) * s_old[idx] + sigmoidf(ig) * tanhf(gg);
        const float dn = sigmoidf(og) * tanhf(sn);
        s_new[idx] = sn;
        sb_new[idx] = f2bf(sn);
        db_new[idx] = f2bf(dn);
        if (d_new != nullptr) d_new[idx] = dn;
    }
}

// ---------------------------------------------------------------------------
extern "C" void kernel_launch(void* const* d_in, const int* in_sizes, int n_in,
                              void* d_out, int out_size, void* d_ws, size_t ws_size,
                              hipStream_t stream) {
    const float* Z      = (const float*)d_in[0];
    const float* d_init = (const float*)d_in[1];
    const float* s_init = (const float*)d_in[2];
    const float* y_real = (const float*)d_in[3];
    const float* vd     = (const float*)d_in[4];
    const float* Wd     = (const float*)d_in[5];
    const float* Ud     = (const float*)d_in[6];
    const float* w      = (const float*)d_in[7];
    const float* b00    = (const float*)d_in[8];
    const float* conv_w = (const float*)d_in[9];
    const float* conv_b = (const float*)d_in[10];
    const float* Wih    = (const float*)d_in[11];
    const float* Whh    = (const float*)d_in[12];
    const float* bih    = (const float*)d_in[13];
    const float* bhh    = (const float*)d_in[14];

    float* ws = (float*)d_ws;
    size_t off = 0;
    unsigned short* Htb = (unsigned short*)(ws + off);  off += (size_t)WINDOW * BH / 2;
    unsigned short* Gb  = (unsigned short*)(ws + off);  off += (size_t)WINDOW * BH / 2;
    unsigned short* dbb[2];
    dbb[0] = (unsigned short*)(ws + off);  off += BH / 2;
    dbb[1] = (unsigned short*)(ws + off);  off += BH / 2;
    unsigned short* sbb[2];
    sbb[0] = (unsigned short*)(ws + off);  off += BH / 2;
    sbb[1] = (unsigned short*)(ws + off);  off += BH / 2;
    float* sbuf[2];
    sbuf[0] = ws + off;  off += BH;
    sbuf[1] = ws + off;  off += BH;
    unsigned short* Wdb  = (unsigned short*)(ws + off);  off += (size_t)HIDDEN * 2 * HIDDEN / 2;
    unsigned short* Udb  = (unsigned short*)(ws + off);  off += (size_t)HIDDEN * HIDDEN / 2;
    unsigned short* Whhb = (unsigned short*)(ws + off);  off += (size_t)H4 * HIDDEN / 2;
    float* hw     = ws + off;  off += (size_t)WINDOW * BATCH;
    float* lpart  = ws + off;  off += (size_t)16 * BATCH;
    float* yr_dot = ws + off;  off += BATCH;
    float* Sacc   = ws + off;  off += 2 * WINDOW;
    float* ctwA   = ws + off;  off += WINDOW + 4;
    int*   flags  = (int*)(ws + off);  off += WINDOW;

    float* out = (float*)d_out;
    float* y_out   = out;
    float* d_out_f = out + BATCH;
    float* s_out_f = out + BATCH + (size_t)BH;

    // --- one-time prep (hw fused into conv; init fused into cvt5) ---
    cvt5_kernel<<<3848, 256, 0, stream>>>(Wd, Wdb, Ud, Udb, Whh, Whhb,
                                          d_init, dbb[0], s_init, sbb[0],
                                          y_real, w, yr_dot, Sacc, flags, ctwA);
    conv_kernel<<<BATCH, 256, 0, stream>>>(Z, conv_w, conv_b, (unsigned int*)Htb, w, hw);
    g_gemm_mfma<<<384 * 4, 256, 0, stream>>>(Htb, Udb, Gb);

    // --- scan over 24 steps: 2 launches/step ---
    const float* s_read = s_init;
    int pp = 0;
    for (int t = 0; t < WINDOW; ++t) {
        const unsigned short* Gtb = Gb + (size_t)t * BH;
        s1_mfma<<<512, 256, 0, stream>>>(dbb[pp], sbb[pp], Wdb, Gtb, vd, lpart);
        const bool last = (t == WINDOW - 1);
        float* s_w = last ? s_out_f : sbuf[t & 1];
        float* d_w = last ? d_out_f : nullptr;
        float* y_w = last ? y_out : nullptr;
        gates_lstm_mfma<<<1024, 256, 0, stream>>>(dbb[pp], Whhb, Wih, bih, bhh, yr_dot,
                                                  lpart, hw + t * BATCH, Sacc, flags,
                                                  ctwA, b00, s_read, s_w, d_w,
                                                  sbb[1 - pp], dbb[1 - pp], y_w, t);
        s_read = s_w;
        pp ^= 1;
    }
}

// Round 16
// 855.265 us; speedup vs baseline: 1.0672x; 1.0672x over previous
//
#include <hip/hip_runtime.h>
#include <math.h>

#define HIDDEN 512
#define WINDOW 24
#define KSZ 3
#define BATCH 2048
#define L_IN 514
#define H4 2048
#define LDT 40                    // padded LDS row stride (shorts) for 32-k tiles
#define BH (BATCH * HIDDEN)

typedef short short8 __attribute__((ext_vector_type(8)));
typedef float floatx4 __attribute__((ext_vector_type(4)));

__device__ __forceinline__ floatx4 mfma16(short8 a, short8 b, floatx4 c) {
    return __builtin_amdgcn_mfma_f32_16x16x32_bf16(a, b, c, 0, 0, 0);
}
__device__ __forceinline__ unsigned short f2bf(float x) {
    union { float f; unsigned u; } v; v.f = x;
    unsigned r = v.u + 0x7fff + ((v.u >> 16) & 1);   // RTNE
    return (unsigned short)(r >> 16);
}
__device__ __forceinline__ float bf2f(unsigned short u) {
    union { unsigned u; float f; } v; v.u = ((unsigned)u) << 16;
    return v.f;
}
__device__ __forceinline__ float sigmoidf(float x) { return 1.f / (1.f + expf(-x)); }

// Direct global->LDS DMA, 16 B per lane (dest = wave-uniform base + lane*16).
__device__ __forceinline__ void gload_lds16(const void* g, void* l) {
    __builtin_amdgcn_global_load_lds(
        (const __attribute__((address_space(1))) void*)g,
        (__attribute__((address_space(3))) void*)l, 16, 0, 0);
}

// ---------------------------------------------------------------------------
// cvt5 + init (verbatim R14): fp32 -> bf16 for Wd, Ud, Whh, d_init, s_init;
// tail blocks do init work. Whh gate-interleaved repack [validated R6].
// ---------------------------------------------------------------------------
__global__ void cvt5_kernel(const float* __restrict__ s0, unsigned short* __restrict__ d0,
                            const float* __restrict__ s1, unsigned short* __restrict__ d1,
                            const float* __restrict__ s2, unsigned short* __restrict__ d2,
                            const float* __restrict__ s3, unsigned short* __restrict__ d3,
                            const float* __restrict__ s4, unsigned short* __restrict__ d4,
                            const float* __restrict__ y_real, const float* __restrict__ w,
                            float* __restrict__ yr_dot, float* __restrict__ Sacc,
                            int* __restrict__ flags, float* __restrict__ ctwA) {
    const int g = blockIdx.x * blockDim.x + threadIdx.x;   // one float4 per thread
    if (g >= 983040) {                                     // init tail: 2048 threads
        const int tid = g - 983040;
        if (tid < BATCH) {
            float s = 0.f;
#pragma unroll
            for (int j = 0; j < WINDOW; ++j) s += y_real[tid * WINDOW + j] * w[j];
            yr_dot[tid] = s;
        }
        if (tid < 2 * WINDOW) Sacc[tid] = 0.f;
        if (tid < WINDOW) flags[tid] = 0;
        if (tid == 0) ctwA[0] = 0.f;
        return;
    }
    const float* src; unsigned short* dst; int off, offd;
    if      (g < 131072) { src = s0; dst = d0; off = g; offd = off; }
    else if (g < 196608) { src = s1; dst = d1; off = g - 131072; offd = off; }
    else if (g < 458752) {
        src = s2; dst = d2; off = g - 196608;
        const int row = off >> 7, seg = off & 127;       // 128 float4 per 512-col row
        const int gg = row >> 9, ii = row & 511;
        const int drow = ((ii >> 4) << 6) + (gg << 4) + (ii & 15);
        offd = drow * 128 + seg;
    }
    else if (g < 720896) { src = s3; dst = d3; off = g - 458752; offd = off; }
    else                 { src = s4; dst = d4; off = g - 720896; offd = off; }
    float4 v = ((const float4*)src)[off];
    uint2 u;
    u.x = (unsigned)f2bf(v.x) | ((unsigned)f2bf(v.y) << 16);
    u.y = (unsigned)f2bf(v.z) | ((unsigned)f2bf(v.w) << 16);
    ((uint2*)dst)[offd] = u;
}

// ---------------------------------------------------------------------------
// conv1d + bias + relu -> Htb bf16 [t][b][i]; FUSED hw (verbatim R14).
// ---------------------------------------------------------------------------
__global__ void conv_kernel(const float* __restrict__ Z, const float* __restrict__ conv_w,
                            const float* __restrict__ conv_b,
                            unsigned int* __restrict__ Htu,
                            const float* __restrict__ w, float* __restrict__ hw) {
    __shared__ float cw[WINDOW * 6];
    __shared__ float cb[WINDOW];
    __shared__ float sm[WINDOW][4];
    const int b = blockIdx.x;
    if (threadIdx.x < WINDOW * 6) cw[threadIdx.x] = conv_w[threadIdx.x];
    if (threadIdx.x < WINDOW) cb[threadIdx.x] = conv_b[threadIdx.x];
    __syncthreads();
    const float* z0 = Z + (size_t)b * L_IN;
    const float* z1 = z0 + (size_t)BATCH * L_IN;
    const int i0 = threadIdx.x * 2;
    const int wave = threadIdx.x >> 6;
    const float a0 = z0[i0], a1 = z0[i0 + 1], a2 = z0[i0 + 2], a3 = z0[i0 + 3];
    const float c0 = z1[i0], c1 = z1[i0 + 1], c2 = z1[i0 + 2], c3 = z1[i0 + 3];
    const float wv0 = w[WINDOW + i0], wv1 = w[WINDOW + i0 + 1];
#pragma unroll
    for (int o = 0; o < WINDOW; ++o) {
        const float* wc = cw + o * 6;
        float v0 = fmaxf(cb[o] + a0 * wc[0] + a1 * wc[1] + a2 * wc[2]
                               + c0 * wc[3] + c1 * wc[4] + c2 * wc[5], 0.f);
        float v1 = fmaxf(cb[o] + a1 * wc[0] + a2 * wc[1] + a3 * wc[2]
                               + c1 * wc[3] + c2 * wc[4] + c3 * wc[5], 0.f);
        const unsigned short h0 = f2bf(v0), h1 = f2bf(v1);
        Htu[((size_t)o * BATCH + b) * 256 + threadIdx.x] =
            (unsigned)h0 | ((unsigned)h1 << 16);
        float c = bf2f(h0) * wv0 + bf2f(h1) * wv1;
#pragma unroll
        for (int m = 1; m < 64; m <<= 1) c += __shfl_xor(c, m, 64);
        if ((threadIdx.x & 63) == 0) sm[o][wave] = c;
    }
    __syncthreads();
    if (threadIdx.x < WINDOW)
        hw[(size_t)threadIdx.x * BATCH + b] =
            sm[threadIdx.x][0] + sm[threadIdx.x][1] + sm[threadIdx.x][2] + sm[threadIdx.x][3];
}

// ---------------------------------------------------------------------------
// Gb = Htb @ Udb^T (verbatim R14 — measured good): 128x128, BK=64, gload_lds
// with both-sides permutation, XCD-clustered swizzle.
// ---------------------------------------------------------------------------
__global__ __launch_bounds__(256) void g_gemm_mfma(const unsigned short* __restrict__ Htb,
                                                   const unsigned short* __restrict__ Udb,
                                                   unsigned short* __restrict__ Gb) {
    __shared__ __align__(16) short As[2 * 8 * 512];   // 2 panels x 8 chunks x 1 KB
    __shared__ __align__(16) short Bs[2 * 8 * 512];
    const int blk = blockIdx.x;                 // 0..1535
    const int xcd = blk & 7;
    const int grp = blk >> 3;                   // 0..191
    const int nt  = grp & 3;                    // n-tile 0..3 (inner on one XCD)
    const int mt  = (grp >> 2) * 8 + xcd;       // m-tile 0..383
    const int tid = threadIdx.x;
    const int wave = tid >> 6, lane = tid & 63;
    const int wm = wave >> 1, wn = wave & 1;
    const int quad = lane >> 4, lr = lane & 15;
    const int m0 = mt * 128, n0 = nt * 128;
    const int wr = lane >> 2;                 // row within 16-row chunk
    const int ws = (lane & 3) ^ (lane >> 4);  // permuted k-seg
    const int rsw = (lr * 4 + (quad ^ (lr >> 2))) * 8;
    floatx4 acc[4][4] = {};
    for (int k0 = 0; k0 < HIDDEN; k0 += 64) {
#pragma unroll
        for (int c8 = 0; c8 < 8; ++c8) {
            const int cc = wave * 8 + c8;          // 0..31
            const int cc2 = cc & 15;
            const int h = cc2 >> 3, ch = cc2 & 7;
            if (cc < 16)
                gload_lds16(Htb + (size_t)(m0 + ch * 16 + wr) * HIDDEN + k0 + 32 * h + ws * 8,
                            As + (h * 8 + ch) * 512);
            else
                gload_lds16(Udb + (size_t)(n0 + ch * 16 + wr) * HIDDEN + k0 + 32 * h + ws * 8,
                            Bs + (h * 8 + ch) * 512);
        }
        __syncthreads();
#pragma unroll
        for (int h = 0; h < 2; ++h) {
            short8 a[4], bv[4];
#pragma unroll
            for (int f = 0; f < 4; ++f) {
                a[f]  = *(const short8*)(As + (h * 8 + wm * 4 + f) * 512 + rsw);
                bv[f] = *(const short8*)(Bs + (h * 8 + wn * 4 + f) * 512 + rsw);
            }
#pragma unroll
            for (int mf = 0; mf < 4; ++mf)
#pragma unroll
                for (int nf = 0; nf < 4; ++nf)
                    acc[mf][nf] = mfma16(a[mf], bv[nf], acc[mf][nf]);
        }
        __syncthreads();
    }
#pragma unroll
    for (int mf = 0; mf < 4; ++mf)
#pragma unroll
        for (int nf = 0; nf < 4; ++nf)
#pragma unroll
            for (int r = 0; r < 4; ++r) {
                const int m = m0 + wm * 64 + mf * 16 + quad * 4 + r;
                const int n = n0 + wn * 64 + nf * 16 + lr;
                Gb[(size_t)m * HIDDEN + n] = f2bf(acc[mf][nf][r]);
            }
}

// ---------------------------------------------------------------------------
// S1, merged passes, BK=64, split accumulators (verbatim R13/R14 — passed).
// ---------------------------------------------------------------------------
__global__ __launch_bounds__(256) void s1_mfma(const unsigned short* __restrict__ db,
                                               const unsigned short* __restrict__ sb,
                                               const unsigned short* __restrict__ Wdb,
                                               const unsigned short* __restrict__ Gtb,
                                               const float* __restrict__ vd,
                                               float* __restrict__ lpart) {
    __shared__ __align__(16) short Asd[2][64 * LDT];
    __shared__ __align__(16) short Ass[2][64 * LDT];
    __shared__ __align__(16) short Bsd[2][32 * LDT];
    __shared__ __align__(16) short Bss[2][32 * LDT];
    __shared__ float red[2][64];
    const int tid = threadIdx.x;
    const int wave = tid >> 6, lane = tid & 63;
    const int wm = wave >> 1, wn = wave & 1;
    const int quad = lane >> 4, lr = lane & 15, qk = quad * 8;
    const int m0 = (blockIdx.x & 31) * 64;
    const int nb = blockIdx.x >> 5;          // 0..15
    const int n0 = nb * 32;
    const int arow = tid >> 2, aseg = tid & 3;
    floatx4 accd[2] = {}, accs[2] = {};
    for (int k0 = 0; k0 < HIDDEN; k0 += 64) {
#pragma unroll
        for (int h = 0; h < 2; ++h) {
            const int kk = k0 + 32 * h;
            *(float4*)(Asd[h] + arow * LDT + aseg * 8) =
                *(const float4*)(db + (size_t)(m0 + arow) * HIDDEN + kk + aseg * 8);
            *(float4*)(Ass[h] + arow * LDT + aseg * 8) =
                *(const float4*)(sb + (size_t)(m0 + arow) * HIDDEN + kk + aseg * 8);
            const int r2 = tid & 127, brow = r2 >> 2, bseg = r2 & 3;
            short* dst = (tid < 128) ? Bsd[h] : Bss[h];
            const int coff = (tid < 128) ? 0 : HIDDEN;
            *(float4*)(dst + brow * LDT + bseg * 8) =
                *(const float4*)(Wdb + (size_t)(n0 + brow) * (2 * HIDDEN) + coff + kk + bseg * 8);
        }
        __syncthreads();
#pragma unroll
        for (int h = 0; h < 2; ++h) {
            short8 ad0 = *(const short8*)(Asd[h] + (wm * 32 + lr) * LDT + qk);
            short8 ad1 = *(const short8*)(Asd[h] + (wm * 32 + 16 + lr) * LDT + qk);
            short8 as0 = *(const short8*)(Ass[h] + (wm * 32 + lr) * LDT + qk);
            short8 as1 = *(const short8*)(Ass[h] + (wm * 32 + 16 + lr) * LDT + qk);
            short8 bd  = *(const short8*)(Bsd[h] + (wn * 16 + lr) * LDT + qk);
            short8 bs  = *(const short8*)(Bss[h] + (wn * 16 + lr) * LDT + qk);
            accd[0] = mfma16(ad0, bd, accd[0]);
            accd[1] = mfma16(ad1, bd, accd[1]);
            accs[0] = mfma16(as0, bs, accs[0]);
            accs[1] = mfma16(as1, bs, accs[1]);
        }
        __syncthreads();
    }
#pragma unroll
    for (int mf = 0; mf < 2; ++mf) {
        float rs[4];
#pragma unroll
        for (int r = 0; r < 4; ++r) {
            const int b = m0 + wm * 32 + mf * 16 + quad * 4 + r;
            const int i = n0 + wn * 16 + lr;
            float v = tanhf(accd[mf][r] + accs[mf][r] + bf2f(Gtb[(size_t)b * HIDDEN + i])) * vd[i];
            for (int msk = 1; msk < 16; msk <<= 1) v += __shfl_xor(v, msk, 16);
            rs[r] = v;
        }
        if (lr == 0)
#pragma unroll
            for (int r = 0; r < 4; ++r)
                red[wn][wm * 32 + mf * 16 + quad * 4 + r] = rs[r];
    }
    __syncthreads();
    if (tid < 64)
        lpart[(size_t)nb * BATCH + m0 + tid] = red[0][tid] + red[1][tid];
}

// ---------------------------------------------------------------------------
// gates+mid+LSTM: REVERTED to R14's 64x128 tile, 512 blocks (measured best),
// with one change: BK=128 — each wave stages one full 32-k half-panel
// (h = wave, 12 chunks each), then 32 MFMAs per barrier-pair, 4 pairs total.
// LDS 48 KB -> still 2 blocks/CU. Fold/flag/epilogue verbatim R14.
// ---------------------------------------------------------------------------
__global__ __launch_bounds__(256) void gates_lstm_mfma(
        const unsigned short* __restrict__ db, const unsigned short* __restrict__ Whhb,
        const float* __restrict__ Wih, const float* __restrict__ bih,
        const float* __restrict__ bhh, const float* __restrict__ yr_dot,
        const float* __restrict__ lpart, const float* __restrict__ hw_t,
        float* __restrict__ Sacc, int* __restrict__ flags,
        float* __restrict__ ctwA, const float* __restrict__ b00,
        const float* __restrict__ s_old, float* __restrict__ s_new,
        float* __restrict__ d_new,
        unsigned short* __restrict__ sb_new, unsigned short* __restrict__ db_new,
        float* __restrict__ y_out, int t) {
    __shared__ __align__(16) short As[4 * 4 * 512];     // 4 panels x 4 chunks x 1 KB
    __shared__ __align__(16) short Bs[4 * 8 * 512];     // 4 panels x 8 chunks x 1 KB
    __shared__ float sSe[2];
    const int tid = threadIdx.x;
    const int wave = tid >> 6, lane = tid & 63;
    const int wm = wave >> 1, wn = wave & 1;
    const int quad = lane >> 4, lr = lane & 15;
    const int mt = blockIdx.x & 31, nt = blockIdx.x >> 5;   // 32 x 16
    const int m0 = mt * 64, n0 = nt * 128;

    // --- mid fold: nt==0 blocks (32) reduce their 64 b-rows of lpart ---
    if (nt == 0 && tid < 64) {
        const int b = m0 + tid;
        float l = 0.f;
#pragma unroll
        for (int p = 0; p < 16; ++p) l += lpart[(size_t)p * BATCH + b];
        float e = expf(l);
        float eh = e * hw_t[b];
#pragma unroll
        for (int m = 1; m < 64; m <<= 1) {
            e  += __shfl_xor(e, m, 64);
            eh += __shfl_xor(eh, m, 64);
        }
        if (tid == 0) {
            __hip_atomic_fetch_add(&Sacc[2 * t], e, __ATOMIC_RELAXED, __HIP_MEMORY_SCOPE_AGENT);
            __hip_atomic_fetch_add(&Sacc[2 * t + 1], eh, __ATOMIC_RELAXED, __HIP_MEMORY_SCOPE_AGENT);
        }
    }
    __syncthreads();   // drains wave0's atomic adds
    if (nt == 0 && tid == 0)
        __hip_atomic_fetch_add(&flags[t], 1, __ATOMIC_RELEASE, __HIP_MEMORY_SCOPE_AGENT);

    // writer-side permutation (per-lane global source for linear LDS dest)
    const int wr = lane >> 2;                 // row within 16-row chunk
    const int ws = (lane & 3) ^ (lane >> 4);  // permuted k-seg
    // reader-side: swizzled short-offset within a chunk
    const int rsw = (lr * 4 + (quad ^ (lr >> 2))) * 8;

    // --- gates GEMM: C[64 b][128 n], n = gate-interleaved i; BK=128 ---
    floatx4 acc[2][4] = {};   // [mf][g]
    for (int k0 = 0; k0 < HIDDEN; k0 += 128) {
        // 48 chunk-DMAs per iteration; wave w stages its own panel h=w
#pragma unroll
        for (int wi = 0; wi < 12; ++wi) {
            const int h = wave;
            const int kk = k0 + 32 * h;
            if (wi < 4)
                gload_lds16(db + (size_t)(m0 + wi * 16 + wr) * HIDDEN + kk + ws * 8,
                            As + (h * 4 + wi) * 512);
            else {
                const int ch = wi - 4;             // B chunk 0..7
                gload_lds16(Whhb + (size_t)(n0 + ch * 16 + wr) * HIDDEN + kk + ws * 8,
                            Bs + (h * 8 + ch) * 512);
            }
        }
        __syncthreads();
#pragma unroll
        for (int h = 0; h < 4; ++h) {
            short8 a0 = *(const short8*)(As + (h * 4 + 2 * wm) * 512 + rsw);
            short8 a1 = *(const short8*)(As + (h * 4 + 2 * wm + 1) * 512 + rsw);
#pragma unroll
            for (int f = 0; f < 4; ++f) {
                short8 bv = *(const short8*)(Bs + (h * 8 + wn * 4 + f) * 512 + rsw);
                acc[0][f] = mfma16(a0, bv, acc[0][f]);
                acc[1][f] = mfma16(a1, bv, acc[1][f]);
            }
        }
        __syncthreads();
    }

    // --- acquire softmax totals (GEMM hid the wait) ---
    if (tid == 0) {
        while (__hip_atomic_load(&flags[t], __ATOMIC_ACQUIRE, __HIP_MEMORY_SCOPE_AGENT) < 32)
            __builtin_amdgcn_s_sleep(2);
        sSe[0] = __hip_atomic_load(&Sacc[2 * t], __ATOMIC_RELAXED, __HIP_MEMORY_SCOPE_AGENT);
        sSe[1] = __hip_atomic_load(&Sacc[2 * t + 1], __ATOMIC_RELAXED, __HIP_MEMORY_SCOPE_AGENT);
    }
    __syncthreads();
    const float ctw = ctwA[t] + sSe[1] / sSe[0];
    const float ys = ctw + b00[0];
    if (blockIdx.x == 0 && tid == 0) ctwA[t + 1] = ctw;   // next launch reads (plain)
    if (y_out != nullptr && nt == 0 && tid < 64)
        y_out[m0 + tid] = yr_dot[m0 + tid] + ys;

    // --- fused LSTM epilogue: thread owns one i, all 4 gates (nf==g) ---
    const int i = ((n0 + wn * 64) >> 2) + lr;
    float wi4[4], cbv[4];
#pragma unroll
    for (int g = 0; g < 4; ++g) {
        wi4[g] = Wih[g * HIDDEN + i];
        cbv[g] = bih[g * HIDDEN + i] + bhh[g * HIDDEN + i];
    }
#pragma unroll
    for (int mf = 0; mf < 2; ++mf)
#pragma unroll
        for (int r = 0; r < 4; ++r) {
            const int b = m0 + wm * 32 + mf * 16 + quad * 4 + r;
            const float yf = yr_dot[b] + ys;
            const size_t idx = (size_t)b * HIDDEN + i;
            const float ig = acc[mf][0][r] + yf * wi4[0] + cbv[0];
            const float fg = acc[mf][1][r] + yf * wi4[1] + cbv[1];
            const float gg = acc[mf][2][r] + yf * wi4[2] + cbv[2];
            const float og = acc[mf][3][r] + yf * wi4[3] + cbv[3];
            const float sn = sigmoidf(fg) * s_old[idx] + sigmoidf(ig) * tanhf(gg);
            const float dn = sigmoidf(og) * tanhf(sn);
            s_new[idx] = sn;
            sb_new[idx] = f2bf(sn);
            db_new[idx] = f2bf(dn);
            if (d_new != nullptr) d_new[idx] = dn;
        }
}

// ---------------------------------------------------------------------------
extern "C" void kernel_launch(void* const* d_in, const int* in_sizes, int n_in,
                              void* d_out, int out_size, void* d_ws, size_t ws_size,
                              hipStream_t stream) {
    const float* Z      = (const float*)d_in[0];
    const float* d_init = (const float*)d_in[1];
    const float* s_init = (const float*)d_in[2];
    const float* y_real = (const float*)d_in[3];
    const float* vd     = (const float*)d_in[4];
    const float* Wd     = (const float*)d_in[5];
    const float* Ud     = (const float*)d_in[6];
    const float* w      = (const float*)d_in[7];
    const float* b00    = (const float*)d_in[8];
    const float* conv_w = (const float*)d_in[9];
    const float* conv_b = (const float*)d_in[10];
    const float* Wih    = (const float*)d_in[11];
    const float* Whh    = (const float*)d_in[12];
    const float* bih    = (const float*)d_in[13];
    const float* bhh    = (const float*)d_in[14];

    float* ws = (float*)d_ws;
    size_t off = 0;
    unsigned short* Htb = (unsigned short*)(ws + off);  off += (size_t)WINDOW * BH / 2;
    unsigned short* Gb  = (unsigned short*)(ws + off);  off += (size_t)WINDOW * BH / 2;
    unsigned short* dbb[2];
    dbb[0] = (unsigned short*)(ws + off);  off += BH / 2;
    dbb[1] = (unsigned short*)(ws + off);  off += BH / 2;
    unsigned short* sbb[2];
    sbb[0] = (unsigned short*)(ws + off);  off += BH / 2;
    sbb[1] = (unsigned short*)(ws + off);  off += BH / 2;
    float* sbuf[2];
    sbuf[0] = ws + off;  off += BH;
    sbuf[1] = ws + off;  off += BH;
    unsigned short* Wdb  = (unsigned short*)(ws + off);  off += (size_t)HIDDEN * 2 * HIDDEN / 2;
    unsigned short* Udb  = (unsigned short*)(ws + off);  off += (size_t)HIDDEN * HIDDEN / 2;
    unsigned short* Whhb = (unsigned short*)(ws + off);  off += (size_t)H4 * HIDDEN / 2;
    float* hw     = ws + off;  off += (size_t)WINDOW * BATCH;
    float* lpart  = ws + off;  off += (size_t)16 * BATCH;
    float* yr_dot = ws + off;  off += BATCH;
    float* Sacc   = ws + off;  off += 2 * WINDOW;
    float* ctwA   = ws + off;  off += WINDOW + 4;
    int*   flags  = (int*)(ws + off);  off += WINDOW;

    float* out = (float*)d_out;
    float* y_out   = out;
    float* d_out_f = out + BATCH;
    float* s_out_f = out + BATCH + (size_t)BH;

    // --- one-time prep (hw fused into conv; init fused into cvt5) ---
    cvt5_kernel<<<3848, 256, 0, stream>>>(Wd, Wdb, Ud, Udb, Whh, Whhb,
                                          d_init, dbb[0], s_init, sbb[0],
                                          y_real, w, yr_dot, Sacc, flags, ctwA);
    conv_kernel<<<BATCH, 256, 0, stream>>>(Z, conv_w, conv_b, (unsigned int*)Htb, w, hw);
    g_gemm_mfma<<<384 * 4, 256, 0, stream>>>(Htb, Udb, Gb);

    // --- scan over 24 steps: 2 launches/step ---
    const float* s_read = s_init;
    int pp = 0;
    for (int t = 0; t < WINDOW; ++t) {
        const unsigned short* Gtb = Gb + (size_t)t * BH;
        s1_mfma<<<512, 256, 0, stream>>>(dbb[pp], sbb[pp], Wdb, Gtb, vd, lpart);
        const bool last = (t == WINDOW - 1);
        float* s_w = last ? s_out_f : sbuf[t & 1];
        float* d_w = last ? d_out_f : nullptr;
        float* y_w = last ? y_out : nullptr;
        gates_lstm_mfma<<<512, 256, 0, stream>>>(dbb[pp], Whhb, Wih, bih, bhh, yr_dot,
                                                 lpart, hw + t * BATCH, Sacc, flags,
                                                 ctwA, b00, s_read, s_w, d_w,
                                                 sbb[1 - pp], dbb[1 - pp], y_w, t);
        s_read = s_w;
        pp ^= 1;
    }
}

// Round 17
// 806.974 us; speedup vs baseline: 1.1311x; 1.0598x over previous
//
#include <hip/hip_runtime.h>
#include <math.h>

#define HIDDEN 512
#define WINDOW 24
#define KSZ 3
#define BATCH 2048
#define L_IN 514
#define H4 2048
#define LDT 40                    // padded LDS row stride (shorts) for 32-k tiles
#define BH (BATCH * HIDDEN)

typedef short short8 __attribute__((ext_vector_type(8)));
typedef float floatx4 __attribute__((ext_vector_type(4)));

__device__ __forceinline__ floatx4 mfma16(short8 a, short8 b, floatx4 c) {
    return __builtin_amdgcn_mfma_f32_16x16x32_bf16(a, b, c, 0, 0, 0);
}
__device__ __forceinline__ unsigned short f2bf(float x) {
    union { float f; unsigned u; } v; v.f = x;
    unsigned r = v.u + 0x7fff + ((v.u >> 16) & 1);   // RTNE
    return (unsigned short)(r >> 16);
}
__device__ __forceinline__ float bf2f(unsigned short u) {
    union { unsigned u; float f; } v; v.u = ((unsigned)u) << 16;
    return v.f;
}
__device__ __forceinline__ float sigmoidf(float x) { return 1.f / (1.f + expf(-x)); }

// Direct global->LDS DMA, 16 B per lane (dest = wave-uniform base + lane*16).
__device__ __forceinline__ void gload_lds16(const void* g, void* l) {
    __builtin_amdgcn_global_load_lds(
        (const __attribute__((address_space(1))) void*)g,
        (__attribute__((address_space(3))) void*)l, 16, 0, 0);
}

// ---------------------------------------------------------------------------
// cvt5 + init (verbatim R14/R16): fp32 -> bf16 for Wd, Ud, Whh, d/s_init;
// tail blocks do init work. Whh gate-interleaved repack [validated R6].
// ---------------------------------------------------------------------------
__global__ void cvt5_kernel(const float* __restrict__ s0, unsigned short* __restrict__ d0,
                            const float* __restrict__ s1, unsigned short* __restrict__ d1,
                            const float* __restrict__ s2, unsigned short* __restrict__ d2,
                            const float* __restrict__ s3, unsigned short* __restrict__ d3,
                            const float* __restrict__ s4, unsigned short* __restrict__ d4,
                            const float* __restrict__ y_real, const float* __restrict__ w,
                            float* __restrict__ yr_dot, float* __restrict__ Sacc,
                            int* __restrict__ flags, float* __restrict__ ctwA) {
    const int g = blockIdx.x * blockDim.x + threadIdx.x;   // one float4 per thread
    if (g >= 983040) {                                     // init tail: 2048 threads
        const int tid = g - 983040;
        if (tid < BATCH) {
            float s = 0.f;
#pragma unroll
            for (int j = 0; j < WINDOW; ++j) s += y_real[tid * WINDOW + j] * w[j];
            yr_dot[tid] = s;
        }
        if (tid < 2 * WINDOW) Sacc[tid] = 0.f;
        if (tid < WINDOW) flags[tid] = 0;
        if (tid == 0) ctwA[0] = 0.f;
        return;
    }
    const float* src; unsigned short* dst; int off, offd;
    if      (g < 131072) { src = s0; dst = d0; off = g; offd = off; }
    else if (g < 196608) { src = s1; dst = d1; off = g - 131072; offd = off; }
    else if (g < 458752) {
        src = s2; dst = d2; off = g - 196608;
        const int row = off >> 7, seg = off & 127;       // 128 float4 per 512-col row
        const int gg = row >> 9, ii = row & 511;
        const int drow = ((ii >> 4) << 6) + (gg << 4) + (ii & 15);
        offd = drow * 128 + seg;
    }
    else if (g < 720896) { src = s3; dst = d3; off = g - 458752; offd = off; }
    else                 { src = s4; dst = d4; off = g - 720896; offd = off; }
    float4 v = ((const float4*)src)[off];
    uint2 u;
    u.x = (unsigned)f2bf(v.x) | ((unsigned)f2bf(v.y) << 16);
    u.y = (unsigned)f2bf(v.z) | ((unsigned)f2bf(v.w) << 16);
    ((uint2*)dst)[offd] = u;
}

// ---------------------------------------------------------------------------
// conv1d + bias + relu -> Htb bf16 [t][b][i]; FUSED hw (verbatim R14/R16).
// ---------------------------------------------------------------------------
__global__ void conv_kernel(const float* __restrict__ Z, const float* __restrict__ conv_w,
                            const float* __restrict__ conv_b,
                            unsigned int* __restrict__ Htu,
                            const float* __restrict__ w, float* __restrict__ hw) {
    __shared__ float cw[WINDOW * 6];
    __shared__ float cb[WINDOW];
    __shared__ float sm[WINDOW][4];
    const int b = blockIdx.x;
    if (threadIdx.x < WINDOW * 6) cw[threadIdx.x] = conv_w[threadIdx.x];
    if (threadIdx.x < WINDOW) cb[threadIdx.x] = conv_b[threadIdx.x];
    __syncthreads();
    const float* z0 = Z + (size_t)b * L_IN;
    const float* z1 = z0 + (size_t)BATCH * L_IN;
    const int i0 = threadIdx.x * 2;
    const int wave = threadIdx.x >> 6;
    const float a0 = z0[i0], a1 = z0[i0 + 1], a2 = z0[i0 + 2], a3 = z0[i0 + 3];
    const float c0 = z1[i0], c1 = z1[i0 + 1], c2 = z1[i0 + 2], c3 = z1[i0 + 3];
    const float wv0 = w[WINDOW + i0], wv1 = w[WINDOW + i0 + 1];
#pragma unroll
    for (int o = 0; o < WINDOW; ++o) {
        const float* wc = cw + o * 6;
        float v0 = fmaxf(cb[o] + a0 * wc[0] + a1 * wc[1] + a2 * wc[2]
                               + c0 * wc[3] + c1 * wc[4] + c2 * wc[5], 0.f);
        float v1 = fmaxf(cb[o] + a1 * wc[0] + a2 * wc[1] + a3 * wc[2]
                               + c1 * wc[3] + c2 * wc[4] + c3 * wc[5], 0.f);
        const unsigned short h0 = f2bf(v0), h1 = f2bf(v1);
        Htu[((size_t)o * BATCH + b) * 256 + threadIdx.x] =
            (unsigned)h0 | ((unsigned)h1 << 16);
        float c = bf2f(h0) * wv0 + bf2f(h1) * wv1;
#pragma unroll
        for (int m = 1; m < 64; m <<= 1) c += __shfl_xor(c, m, 64);
        if ((threadIdx.x & 63) == 0) sm[o][wave] = c;
    }
    __syncthreads();
    if (threadIdx.x < WINDOW)
        hw[(size_t)threadIdx.x * BATCH + b] =
            sm[threadIdx.x][0] + sm[threadIdx.x][1] + sm[threadIdx.x][2] + sm[threadIdx.x][3];
}

// ---------------------------------------------------------------------------
// Gb = Htb @ Udb^T (verbatim R14/R16 — measured good): 128x128, BK=64,
// gload_lds with both-sides permutation, XCD-clustered swizzle.
// ---------------------------------------------------------------------------
__global__ __launch_bounds__(256) void g_gemm_mfma(const unsigned short* __restrict__ Htb,
                                                   const unsigned short* __restrict__ Udb,
                                                   unsigned short* __restrict__ Gb) {
    __shared__ __align__(16) short As[2 * 8 * 512];   // 2 panels x 8 chunks x 1 KB
    __shared__ __align__(16) short Bs[2 * 8 * 512];
    const int blk = blockIdx.x;                 // 0..1535
    const int xcd = blk & 7;
    const int grp = blk >> 3;                   // 0..191
    const int nt  = grp & 3;                    // n-tile 0..3 (inner on one XCD)
    const int mt  = (grp >> 2) * 8 + xcd;       // m-tile 0..383
    const int tid = threadIdx.x;
    const int wave = tid >> 6, lane = tid & 63;
    const int wm = wave >> 1, wn = wave & 1;
    const int quad = lane >> 4, lr = lane & 15;
    const int m0 = mt * 128, n0 = nt * 128;
    const int wr = lane >> 2;                 // row within 16-row chunk
    const int ws = (lane & 3) ^ (lane >> 4);  // permuted k-seg
    const int rsw = (lr * 4 + (quad ^ (lr >> 2))) * 8;
    floatx4 acc[4][4] = {};
    for (int k0 = 0; k0 < HIDDEN; k0 += 64) {
#pragma unroll
        for (int c8 = 0; c8 < 8; ++c8) {
            const int cc = wave * 8 + c8;          // 0..31
            const int cc2 = cc & 15;
            const int h = cc2 >> 3, ch = cc2 & 7;
            if (cc < 16)
                gload_lds16(Htb + (size_t)(m0 + ch * 16 + wr) * HIDDEN + k0 + 32 * h + ws * 8,
                            As + (h * 8 + ch) * 512);
            else
                gload_lds16(Udb + (size_t)(n0 + ch * 16 + wr) * HIDDEN + k0 + 32 * h + ws * 8,
                            Bs + (h * 8 + ch) * 512);
        }
        __syncthreads();
#pragma unroll
        for (int h = 0; h < 2; ++h) {
            short8 a[4], bv[4];
#pragma unroll
            for (int f = 0; f < 4; ++f) {
                a[f]  = *(const short8*)(As + (h * 8 + wm * 4 + f) * 512 + rsw);
                bv[f] = *(const short8*)(Bs + (h * 8 + wn * 4 + f) * 512 + rsw);
            }
#pragma unroll
            for (int mf = 0; mf < 4; ++mf)
#pragma unroll
                for (int nf = 0; nf < 4; ++nf)
                    acc[mf][nf] = mfma16(a[mf], bv[nf], acc[mf][nf]);
        }
        __syncthreads();
    }
#pragma unroll
    for (int mf = 0; mf < 4; ++mf)
#pragma unroll
        for (int nf = 0; nf < 4; ++nf)
#pragma unroll
            for (int r = 0; r < 4; ++r) {
                const int m = m0 + wm * 64 + mf * 16 + quad * 4 + r;
                const int n = n0 + wn * 64 + nf * 16 + lr;
                Gb[(size_t)m * HIDDEN + n] = f2bf(acc[mf][nf][r]);
            }
}

// ---------------------------------------------------------------------------
// S1: NOW gload_lds + both-sides permutation + BK=128 (the combo measured
// -30us on gates in R16). Wave h stages panel h: 12 chunks = 4 d-tile +
// 4 s-tile + 2 Bd + 2 Bs. 16 MFMAs per barrier-pair, 4 pairs (was 8).
// Reader rows wm*32(+16)+lr land on chunks 2wm/2wm+1, within-chunk lr —
// identical round-trip to the gates layout. Epilogue verbatim.
// ---------------------------------------------------------------------------
__global__ __launch_bounds__(256) void s1_mfma(const unsigned short* __restrict__ db,
                                               const unsigned short* __restrict__ sb,
                                               const unsigned short* __restrict__ Wdb,
                                               const unsigned short* __restrict__ Gtb,
                                               const float* __restrict__ vd,
                                               float* __restrict__ lpart) {
    __shared__ __align__(16) short Asd[4 * 4 * 512];   // 4 panels x 4 chunks (d)
    __shared__ __align__(16) short Ass[4 * 4 * 512];   // 4 panels x 4 chunks (s)
    __shared__ __align__(16) short Bsd[4 * 2 * 512];   // 4 panels x 2 chunks (Wd|A)
    __shared__ __align__(16) short Bss[4 * 2 * 512];   // 4 panels x 2 chunks (Wd|B)
    __shared__ float red[2][64];
    const int tid = threadIdx.x;
    const int wave = tid >> 6, lane = tid & 63;
    const int wm = wave >> 1, wn = wave & 1;
    const int quad = lane >> 4, lr = lane & 15;
    const int m0 = (blockIdx.x & 31) * 64;
    const int nb = blockIdx.x >> 5;          // 0..15
    const int n0 = nb * 32;
    // writer-side permutation
    const int wr = lane >> 2;                 // row within 16-row chunk
    const int ws = (lane & 3) ^ (lane >> 4);  // permuted k-seg
    // reader-side swizzled short-offset within a chunk
    const int rsw = (lr * 4 + (quad ^ (lr >> 2))) * 8;

    floatx4 accd[2] = {}, accs[2] = {};
    for (int k0 = 0; k0 < HIDDEN; k0 += 128) {
        const int h = wave;                    // wave stages its own 32-k panel
        const int kk = k0 + 32 * h;
#pragma unroll
        for (int wi = 0; wi < 12; ++wi) {
            if (wi < 4)
                gload_lds16(db + (size_t)(m0 + wi * 16 + wr) * HIDDEN + kk + ws * 8,
                            Asd + (h * 4 + wi) * 512);
            else if (wi < 8)
                gload_lds16(sb + (size_t)(m0 + (wi - 4) * 16 + wr) * HIDDEN + kk + ws * 8,
                            Ass + (h * 4 + (wi - 4)) * 512);
            else if (wi < 10)
                gload_lds16(Wdb + (size_t)(n0 + (wi - 8) * 16 + wr) * (2 * HIDDEN) + kk + ws * 8,
                            Bsd + (h * 2 + (wi - 8)) * 512);
            else
                gload_lds16(Wdb + (size_t)(n0 + (wi - 10) * 16 + wr) * (2 * HIDDEN) + HIDDEN + kk + ws * 8,
                            Bss + (h * 2 + (wi - 10)) * 512);
        }
        __syncthreads();
#pragma unroll
        for (int hh = 0; hh < 4; ++hh) {
            short8 ad0 = *(const short8*)(Asd + (hh * 4 + 2 * wm) * 512 + rsw);
            short8 ad1 = *(const short8*)(Asd + (hh * 4 + 2 * wm + 1) * 512 + rsw);
            short8 as0 = *(const short8*)(Ass + (hh * 4 + 2 * wm) * 512 + rsw);
            short8 as1 = *(const short8*)(Ass + (hh * 4 + 2 * wm + 1) * 512 + rsw);
            short8 bd  = *(const short8*)(Bsd + (hh * 2 + wn) * 512 + rsw);
            short8 bs  = *(const short8*)(Bss + (hh * 2 + wn) * 512 + rsw);
            accd[0] = mfma16(ad0, bd, accd[0]);
            accd[1] = mfma16(ad1, bd, accd[1]);
            accs[0] = mfma16(as0, bs, accs[0]);
            accs[1] = mfma16(as1, bs, accs[1]);
        }
        __syncthreads();
    }
#pragma unroll
    for (int mf = 0; mf < 2; ++mf) {
        float rs[4];
#pragma unroll
        for (int r = 0; r < 4; ++r) {
            const int b = m0 + wm * 32 + mf * 16 + quad * 4 + r;
            const int i = n0 + wn * 16 + lr;
            float v = tanhf(accd[mf][r] + accs[mf][r] + bf2f(Gtb[(size_t)b * HIDDEN + i])) * vd[i];
            for (int msk = 1; msk < 16; msk <<= 1) v += __shfl_xor(v, msk, 16);
            rs[r] = v;
        }
        if (lr == 0)
#pragma unroll
            for (int r = 0; r < 4; ++r)
                red[wn][wm * 32 + mf * 16 + quad * 4 + r] = rs[r];
    }
    __syncthreads();
    if (tid < 64)
        lpart[(size_t)nb * BATCH + m0 + tid] = red[0][tid] + red[1][tid];
}

// ---------------------------------------------------------------------------
// gates+mid+LSTM (verbatim R16 — measured best): 64x128 tile, 512 blocks,
// BK=128 (wave stages its own panel), gload_lds + both-sides permutation,
// fold via agent atomics.
// ---------------------------------------------------------------------------
__global__ __launch_bounds__(256) void gates_lstm_mfma(
        const unsigned short* __restrict__ db, const unsigned short* __restrict__ Whhb,
        const float* __restrict__ Wih, const float* __restrict__ bih,
        const float* __restrict__ bhh, const float* __restrict__ yr_dot,
        const float* __restrict__ lpart, const float* __restrict__ hw_t,
        float* __restrict__ Sacc, int* __restrict__ flags,
        float* __restrict__ ctwA, const float* __restrict__ b00,
        const float* __restrict__ s_old, float* __restrict__ s_new,
        float* __restrict__ d_new,
        unsigned short* __restrict__ sb_new, unsigned short* __restrict__ db_new,
        float* __restrict__ y_out, int t) {
    __shared__ __align__(16) short As[4 * 4 * 512];     // 4 panels x 4 chunks x 1 KB
    __shared__ __align__(16) short Bs[4 * 8 * 512];     // 4 panels x 8 chunks x 1 KB
    __shared__ float sSe[2];
    const int tid = threadIdx.x;
    const int wave = tid >> 6, lane = tid & 63;
    const int wm = wave >> 1, wn = wave & 1;
    const int quad = lane >> 4, lr = lane & 15;
    const int mt = blockIdx.x & 31, nt = blockIdx.x >> 5;   // 32 x 16
    const int m0 = mt * 64, n0 = nt * 128;

    // --- mid fold: nt==0 blocks (32) reduce their 64 b-rows of lpart ---
    if (nt == 0 && tid < 64) {
        const int b = m0 + tid;
        float l = 0.f;
#pragma unroll
        for (int p = 0; p < 16; ++p) l += lpart[(size_t)p * BATCH + b];
        float e = expf(l);
        float eh = e * hw_t[b];
#pragma unroll
        for (int m = 1; m < 64; m <<= 1) {
            e  += __shfl_xor(e, m, 64);
            eh += __shfl_xor(eh, m, 64);
        }
        if (tid == 0) {
            __hip_atomic_fetch_add(&Sacc[2 * t], e, __ATOMIC_RELAXED, __HIP_MEMORY_SCOPE_AGENT);
            __hip_atomic_fetch_add(&Sacc[2 * t + 1], eh, __ATOMIC_RELAXED, __HIP_MEMORY_SCOPE_AGENT);
        }
    }
    __syncthreads();   // drains wave0's atomic adds
    if (nt == 0 && tid == 0)
        __hip_atomic_fetch_add(&flags[t], 1, __ATOMIC_RELEASE, __HIP_MEMORY_SCOPE_AGENT);

    // writer-side permutation (per-lane global source for linear LDS dest)
    const int wr = lane >> 2;                 // row within 16-row chunk
    const int ws = (lane & 3) ^ (lane >> 4);  // permuted k-seg
    // reader-side: swizzled short-offset within a chunk
    const int rsw = (lr * 4 + (quad ^ (lr >> 2))) * 8;

    // --- gates GEMM: C[64 b][128 n], n = gate-interleaved i; BK=128 ---
    floatx4 acc[2][4] = {};   // [mf][g]
    for (int k0 = 0; k0 < HIDDEN; k0 += 128) {
        // 48 chunk-DMAs per iteration; wave w stages its own panel h=w
#pragma unroll
        for (int wi = 0; wi < 12; ++wi) {
            const int h = wave;
            const int kk = k0 + 32 * h;
            if (wi < 4)
                gload_lds16(db + (size_t)(m0 + wi * 16 + wr) * HIDDEN + kk + ws * 8,
                            As + (h * 4 + wi) * 512);
            else {
                const int ch = wi - 4;             // B chunk 0..7
                gload_lds16(Whhb + (size_t)(n0 + ch * 16 + wr) * HIDDEN + kk + ws * 8,
                            Bs + (h * 8 + ch) * 512);
            }
        }
        __syncthreads();
#pragma unroll
        for (int h = 0; h < 4; ++h) {
            short8 a0 = *(const short8*)(As + (h * 4 + 2 * wm) * 512 + rsw);
            short8 a1 = *(const short8*)(As + (h * 4 + 2 * wm + 1) * 512 + rsw);
#pragma unroll
            for (int f = 0; f < 4; ++f) {
                short8 bv = *(const short8*)(Bs + (h * 8 + wn * 4 + f) * 512 + rsw);
                acc[0][f] = mfma16(a0, bv, acc[0][f]);
                acc[1][f] = mfma16(a1, bv, acc[1][f]);
            }
        }
        __syncthreads();
    }

    // --- acquire softmax totals (GEMM hid the wait) ---
    if (tid == 0) {
        while (__hip_atomic_load(&flags[t], __ATOMIC_ACQUIRE, __HIP_MEMORY_SCOPE_AGENT) < 32)
            __builtin_amdgcn_s_sleep(2);
        sSe[0] = __hip_atomic_load(&Sacc[2 * t], __ATOMIC_RELAXED, __HIP_MEMORY_SCOPE_AGENT);
        sSe[1] = __hip_atomic_load(&Sacc[2 * t + 1], __ATOMIC_RELAXED, __HIP_MEMORY_SCOPE_AGENT);
    }
    __syncthreads();
    const float ctw = ctwA[t] + sSe[1] / sSe[0];
    const float ys = ctw + b00[0];
    if (blockIdx.x == 0 && tid == 0) ctwA[t + 1] = ctw;   // next launch reads (plain)
    if (y_out != nullptr && nt == 0 && tid < 64)
        y_out[m0 + tid] = yr_dot[m0 + tid] + ys;

    // --- fused LSTM epilogue: thread owns one i, all 4 gates (nf==g) ---
    const int i = ((n0 + wn * 64) >> 2) + lr;
    float wi4[4], cbv[4];
#pragma unroll
    for (int g = 0; g < 4; ++g) {
        wi4[g] = Wih[g * HIDDEN + i];
        cbv[g] = bih[g * HIDDEN + i] + bhh[g * HIDDEN + i];
    }
#pragma unroll
    for (int mf = 0; mf < 2; ++mf)
#pragma unroll
        for (int r = 0; r < 4; ++r) {
            const int b = m0 + wm * 32 + mf * 16 + quad * 4 + r;
            const float yf = yr_dot[b] + ys;
            const size_t idx = (size_t)b * HIDDEN + i;
            const float ig = acc[mf][0][r] + yf * wi4[0] + cbv[0];
            const float fg = acc[mf][1][r] + yf * wi4[1] + cbv[1];
            const float gg = acc[mf][2][r] + yf * wi4[2] + cbv[2];
            const float og = acc[mf][3][r] + yf * wi4[3] + cbv[3];
            const float sn = sigmoidf(fg) * s_old[idx] + sigmoidf(ig) * tanhf(gg);
            const float dn = sigmoidf(og) * tanhf(sn);
            s_new[idx] = sn;
            sb_new[idx] = f2bf(sn);
            db_new[idx] = f2bf(dn);
            if (d_new != nullptr) d_new[idx] = dn;
        }
}

// ---------------------------------------------------------------------------
extern "C" void kernel_launch(void* const* d_in, const int* in_sizes, int n_in,
                              void* d_out, int out_size, void* d_ws, size_t ws_size,
                              hipStream_t stream) {
    const float* Z      = (const float*)d_in[0];
    const float* d_init = (const float*)d_in[1];
    const float* s_init = (const float*)d_in[2];
    const float* y_real = (const float*)d_in[3];
    const float* vd     = (const float*)d_in[4];
    const float* Wd     = (const float*)d_in[5];
    const float* Ud     = (const float*)d_in[6];
    const float* w      = (const float*)d_in[7];
    const float* b00    = (const float*)d_in[8];
    const float* conv_w = (const float*)d_in[9];
    const float* conv_b = (const float*)d_in[10];
    const float* Wih    = (const float*)d_in[11];
    const float* Whh    = (const float*)d_in[12];
    const float* bih    = (const float*)d_in[13];
    const float* bhh    = (const float*)d_in[14];

    float* ws = (float*)d_ws;
    size_t off = 0;
    unsigned short* Htb = (unsigned short*)(ws + off);  off += (size_t)WINDOW * BH / 2;
    unsigned short* Gb  = (unsigned short*)(ws + off);  off += (size_t)WINDOW * BH / 2;
    unsigned short* dbb[2];
    dbb[0] = (unsigned short*)(ws + off);  off += BH / 2;
    dbb[1] = (unsigned short*)(ws + off);  off += BH / 2;
    unsigned short* sbb[2];
    sbb[0] = (unsigned short*)(ws + off);  off += BH / 2;
    sbb[1] = (unsigned short*)(ws + off);  off += BH / 2;
    float* sbuf[2];
    sbuf[0] = ws + off;  off += BH;
    sbuf[1] = ws + off;  off += BH;
    unsigned short* Wdb  = (unsigned short*)(ws + off);  off += (size_t)HIDDEN * 2 * HIDDEN / 2;
    unsigned short* Udb  = (unsigned short*)(ws + off);  off += (size_t)HIDDEN * HIDDEN / 2;
    unsigned short* Whhb = (unsigned short*)(ws + off);  off += (size_t)H4 * HIDDEN / 2;
    float* hw     = ws + off;  off += (size_t)WINDOW * BATCH;
    float* lpart  = ws + off;  off += (size_t)16 * BATCH;
    float* yr_dot = ws + off;  off += BATCH;
    float* Sacc   = ws + off;  off += 2 * WINDOW;
    float* ctwA   = ws + off;  off += WINDOW + 4;
    int*   flags  = (int*)(ws + off);  off += WINDOW;

    float* out = (float*)d_out;
    float* y_out   = out;
    float* d_out_f = out + BATCH;
    float* s_out_f = out + BATCH + (size_t)BH;

    // --- one-time prep (hw fused into conv; init fused into cvt5) ---
    cvt5_kernel<<<3848, 256, 0, stream>>>(Wd, Wdb, Ud, Udb, Whh, Whhb,
                                          d_init, dbb[0], s_init, sbb[0],
                                          y_real, w, yr_dot, Sacc, flags, ctwA);
    conv_kernel<<<BATCH, 256, 0, stream>>>(Z, conv_w, conv_b, (unsigned int*)Htb, w, hw);
    g_gemm_mfma<<<384 * 4, 256, 0, stream>>>(Htb, Udb, Gb);

    // --- scan over 24 steps: 2 launches/step ---
    const float* s_read = s_init;
    int pp = 0;
    for (int t = 0; t < WINDOW; ++t) {
        const unsigned short* Gtb = Gb + (size_t)t * BH;
        s1_mfma<<<512, 256, 0, stream>>>(dbb[pp], sbb[pp], Wdb, Gtb, vd, lpart);
        const bool last = (t == WINDOW - 1);
        float* s_w = last ? s_out_f : sbuf[t & 1];
        float* d_w = last ? d_out_f : nullptr;
        float* y_w = last ? y_out : nullptr;
        gates_lstm_mfma<<<512, 256, 0, stream>>>(dbb[pp], Whhb, Wih, bih, bhh, yr_dot,
                                                 lpart, hw + t * BATCH, Sacc, flags,
                                                 ctwA, b00, s_read, s_w, d_w,
                                                 sbb[1 - pp], dbb[1 - pp], y_w, t);
        s_read = s_w;
        pp ^= 1;
    }
}